// Round 4
// baseline (84.382 us; speedup 1.0000x reference)
//
#include <hip/hip_runtime.h>
#include <hip/hip_bf16.h>

#define N_NODES 4096
#define BATCH 8
#define FEAT 128
#define CAP 256

typedef float v2f __attribute__((ext_vector_type(2)));

__device__ __forceinline__ unsigned short f2bf(float f) {
    unsigned int u = __float_as_uint(f);
    u += 0x7fffu + ((u >> 16) & 1u);   // RNE (inputs are finite, non-NaN)
    return (unsigned short)(u >> 16);
}

// acc[0..3] (v2f pairs) += p * bf16x8(hv) — packed fp32 FMA friendly.
__device__ __forceinline__ void fma8v(v2f* acc, v2f pp, uint4 hv) {
    unsigned int u;
    v2f t;
    u = hv.x; t[0] = __uint_as_float(u << 16); t[1] = __uint_as_float(u & 0xffff0000u);
    acc[0] += pp * t;
    u = hv.y; t[0] = __uint_as_float(u << 16); t[1] = __uint_as_float(u & 0xffff0000u);
    acc[1] += pp * t;
    u = hv.z; t[0] = __uint_as_float(u << 16); t[1] = __uint_as_float(u & 0xffff0000u);
    acc[2] += pp * t;
    u = hv.w; t[0] = __uint_as_float(u << 16); t[1] = __uint_as_float(u & 0xffff0000u);
    acc[3] += pp * t;
}

// ---------------------------------------------------------------------------
// Kernel 1: dense A [N][N] -> per-row neighbor list (ushort cols) + degree.
// One wave per row; float4 loads, 4 ballots/iter, popc-prefix compaction.
// 0 LDS -> full occupancy for the BW-bound scan.
// ---------------------------------------------------------------------------
__global__ __launch_bounds__(256) void build_adj(const float* __restrict__ A,
                                                 unsigned short* __restrict__ nbr,
                                                 int* __restrict__ deg) {
    int lane = threadIdx.x & 63;
    int row = blockIdx.x * 4 + (threadIdx.x >> 6);
    const float4* ar = (const float4*)(A + (size_t)row * N_NODES);
    unsigned short* lst = nbr + (size_t)row * CAP;
    unsigned long long below = (1ull << lane) - 1ull;
    int cnt = 0;
    for (int c0 = 0; c0 < N_NODES / 4; c0 += 64) {   // 16 iterations
        float4 v = ar[c0 + lane];
        bool f0 = v.x > 0.f, f1 = v.y > 0.f, f2 = v.z > 0.f, f3 = v.w > 0.f;
        unsigned long long m0 = __ballot(f0), m1 = __ballot(f1),
                           m2 = __ballot(f2), m3 = __ballot(f3);
        int pos = cnt + (int)__popcll(m0 & below) + (int)__popcll(m1 & below)
                      + (int)__popcll(m2 & below) + (int)__popcll(m3 & below);
        int colb = 4 * (c0 + lane);
        if (f0) { if (pos < CAP) lst[pos] = (unsigned short)(colb);     ++pos; }
        if (f1) { if (pos < CAP) lst[pos] = (unsigned short)(colb + 1); ++pos; }
        if (f2) { if (pos < CAP) lst[pos] = (unsigned short)(colb + 2); ++pos; }
        if (f3) { if (pos < CAP) lst[pos] = (unsigned short)(colb + 3); ++pos; }
        cnt += (int)__popcll(m0) + (int)__popcll(m1)
             + (int)__popcll(m2) + (int)__popcll(m3);
    }
    if (lane == 0) deg[row] = cnt < CAP ? cnt : CAP;
}

// ---------------------------------------------------------------------------
// Kernel 2: h = x @ W (bf16 out) + fp32 e_src/e_dst epilogue.
// NO LDS: W (64KB) is read directly from global — per wave-step it is 16
// wave-uniform broadcast addresses, which L1/L2 serve at full rate. 2 rows x
// 8 cols per thread, 32 rows/block, 1024 blocks -> 16 waves/CU.
// ---------------------------------------------------------------------------
__global__ __launch_bounds__(256) void gemm_h(const float* __restrict__ x,
                                              const float* __restrict__ W,
                                              const float* __restrict__ a_src,
                                              const float* __restrict__ a_dst,
                                              unsigned short* __restrict__ h,
                                              float* __restrict__ es,
                                              float* __restrict__ ed) {
    int tid = threadIdx.x;
    int colg = tid & 15;
    int rowg = tid >> 4;
    int c0 = colg * 8;
    int m0 = blockIdx.x * 32 + rowg * 2;
    const float* xr = x + (size_t)m0 * FEAT;

    float acc[2][8];
#pragma unroll
    for (int i = 0; i < 2; ++i)
#pragma unroll
        for (int c = 0; c < 8; ++c) acc[i][c] = 0.f;

    for (int k = 0; k < FEAT; k += 4) {
        float4 xv0 = *(const float4*)(xr + k);
        float4 xv1 = *(const float4*)(xr + FEAT + k);
#pragma unroll
        for (int kk = 0; kk < 4; ++kk) {
            float4 wa = *(const float4*)(W + (size_t)(k + kk) * FEAT + c0);
            float4 wb = *(const float4*)(W + (size_t)(k + kk) * FEAT + c0 + 4);
            float x0 = (&xv0.x)[kk];
            float x1 = (&xv1.x)[kk];
            acc[0][0] += x0 * wa.x; acc[0][1] += x0 * wa.y;
            acc[0][2] += x0 * wa.z; acc[0][3] += x0 * wa.w;
            acc[0][4] += x0 * wb.x; acc[0][5] += x0 * wb.y;
            acc[0][6] += x0 * wb.z; acc[0][7] += x0 * wb.w;
            acc[1][0] += x1 * wa.x; acc[1][1] += x1 * wa.y;
            acc[1][2] += x1 * wa.z; acc[1][3] += x1 * wa.w;
            acc[1][4] += x1 * wb.x; acc[1][5] += x1 * wb.y;
            acc[1][6] += x1 * wb.z; acc[1][7] += x1 * wb.w;
        }
    }

    float as[8], ad[8];
#pragma unroll
    for (int c = 0; c < 8; ++c) { as[c] = a_src[c0 + c]; ad[c] = a_dst[c0 + c]; }

#pragma unroll
    for (int i = 0; i < 2; ++i) {
        uint4 pk;
        pk.x = (unsigned int)f2bf(acc[i][0]) | ((unsigned int)f2bf(acc[i][1]) << 16);
        pk.y = (unsigned int)f2bf(acc[i][2]) | ((unsigned int)f2bf(acc[i][3]) << 16);
        pk.z = (unsigned int)f2bf(acc[i][4]) | ((unsigned int)f2bf(acc[i][5]) << 16);
        pk.w = (unsigned int)f2bf(acc[i][6]) | ((unsigned int)f2bf(acc[i][7]) << 16);
        *(uint4*)(h + (size_t)(m0 + i) * FEAT + c0) = pk;

        float ps = 0.f, pd = 0.f;
#pragma unroll
        for (int c = 0; c < 8; ++c) { ps += acc[i][c] * as[c]; pd += acc[i][c] * ad[c]; }
#pragma unroll
        for (int off = 8; off >= 1; off >>= 1) {
            ps += __shfl_xor(ps, off);
            pd += __shfl_xor(pd, off);
        }
        if (colg == 0) { es[m0 + i] = ps; ed[m0 + i] = pd; }
    }
}

// ---------------------------------------------------------------------------
// Kernel 3: per (b,i) masked-softmax + neighbor aggregation.
// One wave per output row; pass 1 caches z/col in registers + row max.
// Pass 2: 4 groups of 16 lanes x 2 chains = 8 neighbors/iter, 8 bf16 cols
// per lane as one uint4, float2 packed FMA accumulation.
// blockIdx&7 = batch -> XCD affinity (h[b] = 1MB, fits per-XCD 4MB L2).
// ---------------------------------------------------------------------------
__global__ __launch_bounds__(256) void aggregate(const unsigned short* __restrict__ h,
                                                 const float* __restrict__ es,
                                                 const float* __restrict__ ed,
                                                 const unsigned short* __restrict__ nbr,
                                                 const int* __restrict__ deg,
                                                 const float* __restrict__ bias,
                                                 float* __restrict__ out) {
    int lane = threadIdx.x & 63;
    int g = lane >> 4;             // neighbor slot within iteration
    int c8 = (lane & 15) * 8;      // this lane's 8 output columns
    int b = blockIdx.x & 7;
    int i = (blockIdx.x >> 3) * 4 + (threadIdx.x >> 6);

    int d = deg[i];
    const unsigned short* lst = nbr + (size_t)i * CAP;
    float esv = es[b * N_NODES + i];
    const float* edb = ed + b * N_NODES;

    // pass 1: z_j = leaky_relu(e_src[i]+e_dst[j], 0.2); row max; cache z & col
    float zv0 = -1e30f, zv1 = -1e30f, zv2 = -1e30f, zv3 = -1e30f;
    int cv0 = 0, cv1 = 0, cv2 = 0, cv3 = 0;
    float m = -1e30f;
#define PASS1(c, zz, cc)                                            \
    if (c * 64 < d) {                                               \
        int j = c * 64 + lane;                                      \
        if (j < d) {                                                \
            cc = lst[j];                                            \
            float z0 = esv + edb[cc];                               \
            zz = z0 > 0.f ? z0 : 0.2f * z0;                         \
        }                                                           \
        m = fmaxf(m, zz);                                           \
    }
    PASS1(0, zv0, cv0)
    PASS1(1, zv1, cv1)
    PASS1(2, zv2, cv2)
    PASS1(3, zv3, cv3)
#undef PASS1
#pragma unroll
    for (int off = 32; off >= 1; off >>= 1) m = fmaxf(m, __shfl_xor(m, off));

    // pass 2: p = exp(z-m); acc += p * h[b,col,:]; s = sum p
    const unsigned short* hb = h + (size_t)b * N_NODES * FEAT;
    v2f acc0[4], acc1[4];
#pragma unroll
    for (int k = 0; k < 4; ++k) { acc0[k] = (v2f)(0.f); acc1[k] = (v2f)(0.f); }
    float s = 0.f;
#define PASS2(c, zz, cc)                                                        \
    if (c * 64 < d) {                                                           \
        float p = __expf(zz - m);  /* inactive lanes: exp(-1e30-m)==0 */        \
        s += p;                                                                 \
        int n = d - c * 64; if (n > 64) n = 64;                                 \
        int nn = (n + 7) & ~7;                                                  \
        for (int jj = 0; jj < nn; jj += 8) {                                    \
            int j0 = jj + g, j1 = jj + 4 + g;                                   \
            float p0 = __shfl(p, j0); int cj0 = __shfl(cc, j0);                 \
            float p1 = __shfl(p, j1); int cj1 = __shfl(cc, j1);                 \
            uint4 h0 = *(const uint4*)(hb + (size_t)cj0 * FEAT + c8);           \
            uint4 h1 = *(const uint4*)(hb + (size_t)cj1 * FEAT + c8);           \
            v2f pp0; pp0[0] = p0; pp0[1] = p0;                                  \
            v2f pp1; pp1[0] = p1; pp1[1] = p1;                                  \
            fma8v(acc0, pp0, h0);                                               \
            fma8v(acc1, pp1, h1);                                               \
        }                                                                       \
    }
    PASS2(0, zv0, cv0)
    PASS2(1, zv1, cv1)
    PASS2(2, zv2, cv2)
    PASS2(3, zv3, cv3)
#undef PASS2

#pragma unroll
    for (int off = 32; off >= 1; off >>= 1) s += __shfl_xor(s, off);
    float inv = 1.0f / s;

    // merge chains, then the 4 neighbor-groups (same c8 across groups)
#pragma unroll
    for (int k = 0; k < 4; ++k) acc0[k] += acc1[k];
#pragma unroll
    for (int k = 0; k < 4; ++k) {
        acc0[k][0] += __shfl_xor(acc0[k][0], 16);
        acc0[k][1] += __shfl_xor(acc0[k][1], 16);
        acc0[k][0] += __shfl_xor(acc0[k][0], 32);
        acc0[k][1] += __shfl_xor(acc0[k][1], 32);
    }

    if (lane < 16) {
        float4 b0 = *(const float4*)(bias + c8);
        float4 b1 = *(const float4*)(bias + c8 + 4);
        float o[8];
        o[0] = acc0[0][0] * inv + b0.x; o[1] = acc0[0][1] * inv + b0.y;
        o[2] = acc0[1][0] * inv + b0.z; o[3] = acc0[1][1] * inv + b0.w;
        o[4] = acc0[2][0] * inv + b1.x; o[5] = acc0[2][1] * inv + b1.y;
        o[6] = acc0[3][0] * inv + b1.z; o[7] = acc0[3][1] * inv + b1.w;
#pragma unroll
        for (int k = 0; k < 8; ++k) o[k] = o[k] > 0.f ? o[k] : 0.3f * o[k];
        float* orow = out + ((size_t)b * N_NODES + i) * FEAT + c8;
        *(float4*)orow = make_float4(o[0], o[1], o[2], o[3]);
        *(float4*)(orow + 4) = make_float4(o[4], o[5], o[6], o[7]);
    }
}

// ---------------------------------------------------------------------------
extern "C" void kernel_launch(void* const* d_in, const int* in_sizes, int n_in,
                              void* d_out, int out_size, void* d_ws, size_t ws_size,
                              hipStream_t stream) {
    const float* x     = (const float*)d_in[0];
    const float* A     = (const float*)d_in[1];
    const float* W     = (const float*)d_in[2];
    const float* bias  = (const float*)d_in[3];
    const float* a_src = (const float*)d_in[4];
    const float* a_dst = (const float*)d_in[5];
    float* out = (float*)d_out;

    // workspace layout (~10.7 MB total)
    char* ws = (char*)d_ws;
    unsigned short* h = (unsigned short*)ws;                  // B*N*C bf16 (8.4 MB)
    float* es = (float*)(h + (size_t)BATCH * N_NODES * FEAT); // B*N floats
    float* ed = es + BATCH * N_NODES;                         // B*N floats
    int*   dg = (int*)(ed + BATCH * N_NODES);                 // N ints
    unsigned short* nb = (unsigned short*)(dg + N_NODES);     // N*CAP ushorts (2 MB)

    hipLaunchKernelGGL(build_adj, dim3(N_NODES / 4), dim3(256), 0, stream, A, nb, dg);
    hipLaunchKernelGGL(gemm_h, dim3(BATCH * N_NODES / 32), dim3(256), 0, stream,
                       x, W, a_src, a_dst, h, es, ed);
    hipLaunchKernelGGL(aggregate, dim3(BATCH * N_NODES / 4), dim3(256), 0, stream,
                       h, es, ed, nb, dg, bias, out);
}

// Round 5
// 73.965 us; speedup vs baseline: 1.1408x; 1.1408x over previous
//
#include <hip/hip_runtime.h>
#include <hip/hip_bf16.h>

#define N_NODES 4096
#define BATCH 8
#define FEAT 128
#define CAPQ 128     // per-quarter neighbor cap
#define CAP 256      // merged per-row cap

typedef float v2f __attribute__((ext_vector_type(2)));

__device__ __forceinline__ unsigned short f2bf(float f) {
    unsigned int u = __float_as_uint(f);
    u += 0x7fffu + ((u >> 16) & 1u);   // RNE (finite, non-NaN here)
    return (unsigned short)(u >> 16);
}

// acc[0..3] (float2 pairs) += p * bf16x8(hv)
__device__ __forceinline__ void fma8v(v2f* acc, v2f pp, uint4 hv) {
    unsigned int u;
    v2f t;
    u = hv.x; t[0] = __uint_as_float(u << 16); t[1] = __uint_as_float(u & 0xffff0000u);
    acc[0] += pp * t;
    u = hv.y; t[0] = __uint_as_float(u << 16); t[1] = __uint_as_float(u & 0xffff0000u);
    acc[1] += pp * t;
    u = hv.z; t[0] = __uint_as_float(u << 16); t[1] = __uint_as_float(u & 0xffff0000u);
    acc[2] += pp * t;
    u = hv.w; t[0] = __uint_as_float(u << 16); t[1] = __uint_as_float(u & 0xffff0000u);
    acc[3] += pp * t;
}

// ---------------------------------------------------------------------------
// Kernel 1: h = x @ W (bf16 out) + fp32 e_src/e_dst epilogue.
// W in LDS with SPLIT float4 layout: Wl4[k*32 + part*16 + colg] so the 16
// colg lanes read at 16B stride -> start banks 4l mod 32 -> all 32 banks,
// only free 2-way aliasing (vs 32B stride = 4-way conflict seen in R3).
// 4 rows x 8 cols per thread, 64 rows/block, 512 blocks.
// ---------------------------------------------------------------------------
__global__ __launch_bounds__(256) void gemm_h(const float* __restrict__ x,
                                              const float* __restrict__ W,
                                              const float* __restrict__ a_src,
                                              const float* __restrict__ a_dst,
                                              unsigned short* __restrict__ h,
                                              float* __restrict__ es,
                                              float* __restrict__ ed) {
    __shared__ float4 Wl4[FEAT * 32];   // 64 KB
    int tid = threadIdx.x;
    {
        const float4* Wv = (const float4*)W;   // (k, j): j = 0..31, cols 4j..4j+3
        for (int i = tid; i < FEAT * 32; i += 256) {
            int k = i >> 5, j = i & 31;
            // even j -> A-part (first float4 of colg=j/2), odd j -> B-part
            Wl4[k * 32 + ((j & 1) << 4) + (j >> 1)] = Wv[i];
        }
    }
    __syncthreads();

    int colg = tid & 15;
    int rowg = tid >> 4;
    int c0 = colg * 8;
    int m0 = blockIdx.x * 64 + rowg * 4;
    const float* xr = x + (size_t)m0 * FEAT;

    float acc[4][8];
#pragma unroll
    for (int i = 0; i < 4; ++i)
#pragma unroll
        for (int c = 0; c < 8; ++c) acc[i][c] = 0.f;

    for (int k = 0; k < FEAT; k += 4) {
        float4 xv[4];
#pragma unroll
        for (int i = 0; i < 4; ++i) xv[i] = *(const float4*)(xr + i * FEAT + k);
#pragma unroll
        for (int kk = 0; kk < 4; ++kk) {
            float4 wa = Wl4[(k + kk) * 32 + colg];
            float4 wb = Wl4[(k + kk) * 32 + 16 + colg];
#pragma unroll
            for (int i = 0; i < 4; ++i) {
                float xs = (&xv[i].x)[kk];
                acc[i][0] += xs * wa.x; acc[i][1] += xs * wa.y;
                acc[i][2] += xs * wa.z; acc[i][3] += xs * wa.w;
                acc[i][4] += xs * wb.x; acc[i][5] += xs * wb.y;
                acc[i][6] += xs * wb.z; acc[i][7] += xs * wb.w;
            }
        }
    }

    float as[8], ad[8];
#pragma unroll
    for (int c = 0; c < 8; ++c) { as[c] = a_src[c0 + c]; ad[c] = a_dst[c0 + c]; }

#pragma unroll
    for (int i = 0; i < 4; ++i) {
        uint4 pk;
        pk.x = (unsigned int)f2bf(acc[i][0]) | ((unsigned int)f2bf(acc[i][1]) << 16);
        pk.y = (unsigned int)f2bf(acc[i][2]) | ((unsigned int)f2bf(acc[i][3]) << 16);
        pk.z = (unsigned int)f2bf(acc[i][4]) | ((unsigned int)f2bf(acc[i][5]) << 16);
        pk.w = (unsigned int)f2bf(acc[i][6]) | ((unsigned int)f2bf(acc[i][7]) << 16);
        *(uint4*)(h + (size_t)(m0 + i) * FEAT + c0) = pk;

        float ps = 0.f, pd = 0.f;
#pragma unroll
        for (int c = 0; c < 8; ++c) { ps += acc[i][c] * as[c]; pd += acc[i][c] * ad[c]; }
#pragma unroll
        for (int off = 8; off >= 1; off >>= 1) {
            ps += __shfl_xor(ps, off);
            pd += __shfl_xor(pd, off);
        }
        if (colg == 0) { es[m0 + i] = ps; ed[m0 + i] = pd; }
    }
}

// ---------------------------------------------------------------------------
// Kernel 2: fused A-scan + masked-softmax + aggregation. One block per node.
// Phase 1: wave w ballot-compacts A[i, w*1024 .. +1024) into an LDS segment;
//          counts are prefix-summed and segments merged into one LDS list.
//          (HBM scan overlaps other blocks' L2/L3 h-gathers.)
// Phase 2: wave w aggregates batches b=w and b=w+4 using the shared list.
// ---------------------------------------------------------------------------
__global__ __launch_bounds__(256) void scan_agg(const float* __restrict__ A,
                                                const unsigned short* __restrict__ h,
                                                const float* __restrict__ es,
                                                const float* __restrict__ ed,
                                                const float* __restrict__ bias,
                                                float* __restrict__ out) {
    __shared__ unsigned short seg[4 * CAPQ];
    __shared__ unsigned short fl[CAP];
    __shared__ int scnt[4];

    int tid = threadIdx.x;
    int lane = tid & 63;
    int w = tid >> 6;
    int i = blockIdx.x;

    // ---- phase 1: scan quarter-row, ballot-compact into seg[w*CAPQ..] ----
    {
        const float4* ar = (const float4*)(A + (size_t)i * N_NODES);
        unsigned long long below = (1ull << lane) - 1ull;
        int cnt = 0;
#pragma unroll
        for (int c0 = 0; c0 < 4; ++c0) {
            int idx = w * 256 + c0 * 64 + lane;
            float4 v = ar[idx];
            bool f0 = v.x > 0.f, f1 = v.y > 0.f, f2 = v.z > 0.f, f3 = v.w > 0.f;
            unsigned long long m0 = __ballot(f0), m1 = __ballot(f1),
                               m2 = __ballot(f2), m3 = __ballot(f3);
            int pos = cnt + (int)__popcll(m0 & below) + (int)__popcll(m1 & below)
                          + (int)__popcll(m2 & below) + (int)__popcll(m3 & below);
            int colb = 4 * idx;
            if (f0) { if (pos < CAPQ) seg[w * CAPQ + pos] = (unsigned short)(colb);     ++pos; }
            if (f1) { if (pos < CAPQ) seg[w * CAPQ + pos] = (unsigned short)(colb + 1); ++pos; }
            if (f2) { if (pos < CAPQ) seg[w * CAPQ + pos] = (unsigned short)(colb + 2); ++pos; }
            if (f3) { if (pos < CAPQ) seg[w * CAPQ + pos] = (unsigned short)(colb + 3); ++pos; }
            cnt += (int)__popcll(m0) + (int)__popcll(m1)
                 + (int)__popcll(m2) + (int)__popcll(m3);
        }
        if (lane == 0) scnt[w] = cnt < CAPQ ? cnt : CAPQ;
    }
    __syncthreads();

    int c0n = scnt[0], c1n = scnt[1], c2n = scnt[2], c3n = scnt[3];
    int off = (w > 0 ? c0n : 0) + (w > 1 ? c1n : 0) + (w > 2 ? c2n : 0);
    int cw = scnt[w];
    for (int t = lane; t < cw; t += 64) {
        int dst = off + t;
        if (dst < CAP) fl[dst] = seg[w * CAPQ + t];
    }
    int d = c0n + c1n + c2n + c3n;
    if (d > CAP) d = CAP;
    __syncthreads();

    // ---- phase 2: each wave aggregates batches b = w and b = w+4 ----
    int g = lane >> 4;            // neighbor slot group
    int c8 = (lane & 15) * 8;     // 8 output columns per lane

#pragma unroll
    for (int bb = 0; bb < 2; ++bb) {
        int b = w + bb * 4;
        float esv = es[b * N_NODES + i];
        const float* edb = ed + b * N_NODES;

        // pass 1: z/col cached in regs + row max
        float zv0 = -1e30f, zv1 = -1e30f, zv2 = -1e30f, zv3 = -1e30f;
        int cv0 = 0, cv1 = 0, cv2 = 0, cv3 = 0;
        float m = -1e30f;
#define PASS1(c, zz, cc)                                            \
        if (c * 64 < d) {                                           \
            int j = c * 64 + lane;                                  \
            if (j < d) {                                            \
                cc = fl[j];                                         \
                float z0 = esv + edb[cc];                           \
                zz = z0 > 0.f ? z0 : 0.2f * z0;                     \
            }                                                       \
            m = fmaxf(m, zz);                                       \
        }
        PASS1(0, zv0, cv0)
        PASS1(1, zv1, cv1)
        PASS1(2, zv2, cv2)
        PASS1(3, zv3, cv3)
#undef PASS1
#pragma unroll
        for (int o = 32; o >= 1; o >>= 1) m = fmaxf(m, __shfl_xor(m, o));

        // pass 2: p = exp(z-m); acc += p * h[b,col,:]; s = sum p
        const unsigned short* hb = h + (size_t)b * N_NODES * FEAT;
        v2f acc0[4], acc1[4];
#pragma unroll
        for (int k = 0; k < 4; ++k) { acc0[k] = (v2f)(0.f); acc1[k] = (v2f)(0.f); }
        float s = 0.f;
#define PASS2(c, zz, cc)                                                        \
        if (c * 64 < d) {                                                       \
            float p = __expf(zz - m);                                           \
            s += p;                                                             \
            int n = d - c * 64; if (n > 64) n = 64;                             \
            int nn = (n + 7) & ~7;                                              \
            for (int jj = 0; jj < nn; jj += 8) {                                \
                int j0 = jj + g, j1 = jj + 4 + g;                               \
                float p0 = __shfl(p, j0); int cj0 = __shfl(cc, j0);             \
                float p1 = __shfl(p, j1); int cj1 = __shfl(cc, j1);             \
                uint4 h0 = *(const uint4*)(hb + (size_t)cj0 * FEAT + c8);       \
                uint4 h1 = *(const uint4*)(hb + (size_t)cj1 * FEAT + c8);       \
                v2f pp0; pp0[0] = p0; pp0[1] = p0;                              \
                v2f pp1; pp1[0] = p1; pp1[1] = p1;                              \
                fma8v(acc0, pp0, h0);                                           \
                fma8v(acc1, pp1, h1);                                           \
            }                                                                   \
        }
        PASS2(0, zv0, cv0)
        PASS2(1, zv1, cv1)
        PASS2(2, zv2, cv2)
        PASS2(3, zv3, cv3)
#undef PASS2

#pragma unroll
        for (int o = 32; o >= 1; o >>= 1) s += __shfl_xor(s, o);
        float inv = 1.0f / s;

#pragma unroll
        for (int k = 0; k < 4; ++k) acc0[k] += acc1[k];
#pragma unroll
        for (int k = 0; k < 4; ++k) {
            acc0[k][0] += __shfl_xor(acc0[k][0], 16);
            acc0[k][1] += __shfl_xor(acc0[k][1], 16);
            acc0[k][0] += __shfl_xor(acc0[k][0], 32);
            acc0[k][1] += __shfl_xor(acc0[k][1], 32);
        }

        if (lane < 16) {
            float4 b0 = *(const float4*)(bias + c8);
            float4 b1 = *(const float4*)(bias + c8 + 4);
            float o[8];
            o[0] = acc0[0][0] * inv + b0.x; o[1] = acc0[0][1] * inv + b0.y;
            o[2] = acc0[1][0] * inv + b0.z; o[3] = acc0[1][1] * inv + b0.w;
            o[4] = acc0[2][0] * inv + b1.x; o[5] = acc0[2][1] * inv + b1.y;
            o[6] = acc0[3][0] * inv + b1.z; o[7] = acc0[3][1] * inv + b1.w;
#pragma unroll
            for (int k = 0; k < 8; ++k) o[k] = o[k] > 0.f ? o[k] : 0.3f * o[k];
            float* orow = out + ((size_t)b * N_NODES + i) * FEAT + c8;
            *(float4*)orow = make_float4(o[0], o[1], o[2], o[3]);
            *(float4*)(orow + 4) = make_float4(o[4], o[5], o[6], o[7]);
        }
    }
}

// ---------------------------------------------------------------------------
extern "C" void kernel_launch(void* const* d_in, const int* in_sizes, int n_in,
                              void* d_out, int out_size, void* d_ws, size_t ws_size,
                              hipStream_t stream) {
    const float* x     = (const float*)d_in[0];
    const float* A     = (const float*)d_in[1];
    const float* W     = (const float*)d_in[2];
    const float* bias  = (const float*)d_in[3];
    const float* a_src = (const float*)d_in[4];
    const float* a_dst = (const float*)d_in[5];
    float* out = (float*)d_out;

    // workspace layout (~8.7 MB total)
    char* ws = (char*)d_ws;
    unsigned short* h = (unsigned short*)ws;                  // B*N*C bf16 (8.4 MB)
    float* es = (float*)(h + (size_t)BATCH * N_NODES * FEAT); // B*N floats
    float* ed = es + BATCH * N_NODES;                         // B*N floats

    hipLaunchKernelGGL(gemm_h, dim3(BATCH * N_NODES / 64), dim3(256), 0, stream,
                       x, W, a_src, a_dst, h, es, ed);
    hipLaunchKernelGGL(scan_agg, dim3(N_NODES), dim3(256), 0, stream,
                       A, h, es, ed, bias, out);
}

// Round 6
// 65.749 us; speedup vs baseline: 1.2834x; 1.1250x over previous
//
#include <hip/hip_runtime.h>
#include <hip/hip_bf16.h>

#define N_NODES 4096
#define BATCH 8
#define FEAT 128
#define CAP 256

typedef float v2f __attribute__((ext_vector_type(2)));

__device__ __forceinline__ unsigned short f2bf(float f) {
    unsigned int u = __float_as_uint(f);
    u += 0x7fffu + ((u >> 16) & 1u);   // RNE (finite, non-NaN here)
    return (unsigned short)(u >> 16);
}

// acc[0..3] (float2 pairs) += p * bf16x8(hv)
__device__ __forceinline__ void fma8v(v2f* acc, v2f pp, uint4 hv) {
    unsigned int u;
    v2f t;
    u = hv.x; t[0] = __uint_as_float(u << 16); t[1] = __uint_as_float(u & 0xffff0000u);
    acc[0] += pp * t;
    u = hv.y; t[0] = __uint_as_float(u << 16); t[1] = __uint_as_float(u & 0xffff0000u);
    acc[1] += pp * t;
    u = hv.z; t[0] = __uint_as_float(u << 16); t[1] = __uint_as_float(u & 0xffff0000u);
    acc[2] += pp * t;
    u = hv.w; t[0] = __uint_as_float(u << 16); t[1] = __uint_as_float(u & 0xffff0000u);
    acc[3] += pp * t;
}

// ---------------------------------------------------------------------------
// Fused prep, role-split by blockIdx%3:
//   %3==0 (512 blocks): GEMM role — h = x@W (bf16) + fp32 e_src/e_dst.
//       W staged in 16KB LDS chunks (K-tiled x4) with the split-float4
//       bank-free layout (R5-verified: 0 conflicts). 16KB (not 64KB!) so the
//       scan role keeps ~20 waves/CU for HBM latency hiding (R3's bug).
//   else (1024 blocks): scan role — A row -> ushort neighbor list + degree.
// The two roles overlap: scan saturates VMEM/HBM while GEMM fills VALU.
// ---------------------------------------------------------------------------
__global__ __launch_bounds__(256) void prep(const float* __restrict__ x,
                                            const float* __restrict__ A,
                                            const float* __restrict__ W,
                                            const float* __restrict__ a_src,
                                            const float* __restrict__ a_dst,
                                            unsigned short* __restrict__ h,
                                            float* __restrict__ es,
                                            float* __restrict__ ed,
                                            unsigned short* __restrict__ nbr,
                                            int* __restrict__ deg) {
    __shared__ float4 Wl4[32 * 32];   // 16 KB, one K-chunk of W
    int bid = blockIdx.x;
    int tid = threadIdx.x;

    if (bid % 3 == 0) {
        // ------------------- GEMM role: 64 rows per block -------------------
        int gb = bid / 3;
        int colg = tid & 15;
        int rowg = tid >> 4;
        int c0 = colg * 8;
        int m0 = gb * 64 + rowg * 4;
        const float* xr = x + (size_t)m0 * FEAT;
        const float4* Wv = (const float4*)W;   // index (k*32 + j)

        float acc[4][8];
#pragma unroll
        for (int i = 0; i < 4; ++i)
#pragma unroll
            for (int c = 0; c < 8; ++c) acc[i][c] = 0.f;

        for (int kc = 0; kc < 4; ++kc) {       // K-chunks of 32
            __syncthreads();
            for (int t = tid; t < 32 * 32; t += 256) {
                int kk = t >> 5, j = t & 31;
                Wl4[kk * 32 + ((j & 1) << 4) + (j >> 1)] = Wv[(kc * 32 + kk) * 32 + j];
            }
            __syncthreads();
#pragma unroll 2
            for (int k = 0; k < 32; k += 4) {
                float4 xv[4];
#pragma unroll
                for (int i = 0; i < 4; ++i)
                    xv[i] = *(const float4*)(xr + i * FEAT + kc * 32 + k);
#pragma unroll
                for (int kk = 0; kk < 4; ++kk) {
                    float4 wa = Wl4[(k + kk) * 32 + colg];
                    float4 wb = Wl4[(k + kk) * 32 + 16 + colg];
#pragma unroll
                    for (int i = 0; i < 4; ++i) {
                        float xs = (&xv[i].x)[kk];
                        acc[i][0] += xs * wa.x; acc[i][1] += xs * wa.y;
                        acc[i][2] += xs * wa.z; acc[i][3] += xs * wa.w;
                        acc[i][4] += xs * wb.x; acc[i][5] += xs * wb.y;
                        acc[i][6] += xs * wb.z; acc[i][7] += xs * wb.w;
                    }
                }
            }
        }

        float as[8], ad[8];
#pragma unroll
        for (int c = 0; c < 8; ++c) { as[c] = a_src[c0 + c]; ad[c] = a_dst[c0 + c]; }

#pragma unroll
        for (int i = 0; i < 4; ++i) {
            uint4 pk;
            pk.x = (unsigned int)f2bf(acc[i][0]) | ((unsigned int)f2bf(acc[i][1]) << 16);
            pk.y = (unsigned int)f2bf(acc[i][2]) | ((unsigned int)f2bf(acc[i][3]) << 16);
            pk.z = (unsigned int)f2bf(acc[i][4]) | ((unsigned int)f2bf(acc[i][5]) << 16);
            pk.w = (unsigned int)f2bf(acc[i][6]) | ((unsigned int)f2bf(acc[i][7]) << 16);
            *(uint4*)(h + (size_t)(m0 + i) * FEAT + c0) = pk;

            float ps = 0.f, pd = 0.f;
#pragma unroll
            for (int c = 0; c < 8; ++c) { ps += acc[i][c] * as[c]; pd += acc[i][c] * ad[c]; }
#pragma unroll
            for (int off = 8; off >= 1; off >>= 1) {
                ps += __shfl_xor(ps, off);
                pd += __shfl_xor(pd, off);
            }
            if (colg == 0) { es[m0 + i] = ps; ed[m0 + i] = pd; }
        }
    } else {
        // ---------------- scan role: 4 rows per block ------------------
        int ab = (bid / 3) * 2 + (bid % 3 - 1);       // 0..1023
        int lane = tid & 63;
        int row = ab * 4 + (tid >> 6);
        const float4* ar = (const float4*)(A + (size_t)row * N_NODES);
        unsigned short* lst = nbr + (size_t)row * CAP;
        unsigned long long below = (1ull << lane) - 1ull;
        int cnt = 0;
        for (int c0 = 0; c0 < N_NODES / 4; c0 += 64) {   // 16 iterations
            float4 v = ar[c0 + lane];
            bool f0 = v.x > 0.f, f1 = v.y > 0.f, f2 = v.z > 0.f, f3 = v.w > 0.f;
            unsigned long long m0 = __ballot(f0), m1 = __ballot(f1),
                               m2 = __ballot(f2), m3 = __ballot(f3);
            int pos = cnt + (int)__popcll(m0 & below) + (int)__popcll(m1 & below)
                          + (int)__popcll(m2 & below) + (int)__popcll(m3 & below);
            int colb = 4 * (c0 + lane);
            if (f0) { if (pos < CAP) lst[pos] = (unsigned short)(colb);     ++pos; }
            if (f1) { if (pos < CAP) lst[pos] = (unsigned short)(colb + 1); ++pos; }
            if (f2) { if (pos < CAP) lst[pos] = (unsigned short)(colb + 2); ++pos; }
            if (f3) { if (pos < CAP) lst[pos] = (unsigned short)(colb + 3); ++pos; }
            cnt += (int)__popcll(m0) + (int)__popcll(m1)
                 + (int)__popcll(m2) + (int)__popcll(m3);
        }
        if (lane == 0) deg[row] = cnt < CAP ? cnt : CAP;
    }
}

// ---------------------------------------------------------------------------
// Aggregate: one wave per (b,i); z/col cached in regs from the max pass.
// Pass 2: 4 groups of 16 lanes x 2 chains = 8 neighbors/iter, 8 bf16 cols
// per lane as one uint4, float2 packed FMA.
// blockIdx&7 = batch -> XCD affinity (h[b] = 1MB, fits per-XCD 4MB L2).
// ---------------------------------------------------------------------------
__global__ __launch_bounds__(256) void aggregate(const unsigned short* __restrict__ h,
                                                 const float* __restrict__ es,
                                                 const float* __restrict__ ed,
                                                 const unsigned short* __restrict__ nbr,
                                                 const int* __restrict__ deg,
                                                 const float* __restrict__ bias,
                                                 float* __restrict__ out) {
    int lane = threadIdx.x & 63;
    int g = lane >> 4;             // neighbor slot within iteration
    int c8 = (lane & 15) * 8;      // this lane's 8 output columns
    int b = blockIdx.x & 7;
    int i = (blockIdx.x >> 3) * 4 + (threadIdx.x >> 6);

    int d = deg[i];
    const unsigned short* lst = nbr + (size_t)i * CAP;
    float esv = es[b * N_NODES + i];
    const float* edb = ed + b * N_NODES;

    float zv0 = -1e30f, zv1 = -1e30f, zv2 = -1e30f, zv3 = -1e30f;
    int cv0 = 0, cv1 = 0, cv2 = 0, cv3 = 0;
    float m = -1e30f;
#define PASS1(c, zz, cc)                                            \
    if (c * 64 < d) {                                               \
        int j = c * 64 + lane;                                      \
        if (j < d) {                                                \
            cc = lst[j];                                            \
            float z0 = esv + edb[cc];                               \
            zz = z0 > 0.f ? z0 : 0.2f * z0;                         \
        }                                                           \
        m = fmaxf(m, zz);                                           \
    }
    PASS1(0, zv0, cv0)
    PASS1(1, zv1, cv1)
    PASS1(2, zv2, cv2)
    PASS1(3, zv3, cv3)
#undef PASS1
#pragma unroll
    for (int off = 32; off >= 1; off >>= 1) m = fmaxf(m, __shfl_xor(m, off));

    const unsigned short* hb = h + (size_t)b * N_NODES * FEAT;
    v2f acc0[4], acc1[4];
#pragma unroll
    for (int k = 0; k < 4; ++k) { acc0[k] = (v2f)(0.f); acc1[k] = (v2f)(0.f); }
    float s = 0.f;
#define PASS2(c, zz, cc)                                                        \
    if (c * 64 < d) {                                                           \
        float p = __expf(zz - m);  /* inactive lanes: exp(-1e30-m)==0 */        \
        s += p;                                                                 \
        int n = d - c * 64; if (n > 64) n = 64;                                 \
        int nn = (n + 7) & ~7;                                                  \
        for (int jj = 0; jj < nn; jj += 8) {                                    \
            int j0 = jj + g, j1 = jj + 4 + g;                                   \
            float p0 = __shfl(p, j0); int cj0 = __shfl(cc, j0);                 \
            float p1 = __shfl(p, j1); int cj1 = __shfl(cc, j1);                 \
            uint4 h0 = *(const uint4*)(hb + (size_t)cj0 * FEAT + c8);           \
            uint4 h1 = *(const uint4*)(hb + (size_t)cj1 * FEAT + c8);           \
            v2f pp0; pp0[0] = p0; pp0[1] = p0;                                  \
            v2f pp1; pp1[0] = p1; pp1[1] = p1;                                  \
            fma8v(acc0, pp0, h0);                                               \
            fma8v(acc1, pp1, h1);                                               \
        }                                                                       \
    }
    PASS2(0, zv0, cv0)
    PASS2(1, zv1, cv1)
    PASS2(2, zv2, cv2)
    PASS2(3, zv3, cv3)
#undef PASS2

#pragma unroll
    for (int off = 32; off >= 1; off >>= 1) s += __shfl_xor(s, off);
    float inv = 1.0f / s;

#pragma unroll
    for (int k = 0; k < 4; ++k) acc0[k] += acc1[k];
#pragma unroll
    for (int k = 0; k < 4; ++k) {
        acc0[k][0] += __shfl_xor(acc0[k][0], 16);
        acc0[k][1] += __shfl_xor(acc0[k][1], 16);
        acc0[k][0] += __shfl_xor(acc0[k][0], 32);
        acc0[k][1] += __shfl_xor(acc0[k][1], 32);
    }

    if (lane < 16) {
        float4 b0 = *(const float4*)(bias + c8);
        float4 b1 = *(const float4*)(bias + c8 + 4);
        float o[8];
        o[0] = acc0[0][0] * inv + b0.x; o[1] = acc0[0][1] * inv + b0.y;
        o[2] = acc0[1][0] * inv + b0.z; o[3] = acc0[1][1] * inv + b0.w;
        o[4] = acc0[2][0] * inv + b1.x; o[5] = acc0[2][1] * inv + b1.y;
        o[6] = acc0[3][0] * inv + b1.z; o[7] = acc0[3][1] * inv + b1.w;
#pragma unroll
        for (int k = 0; k < 8; ++k) o[k] = o[k] > 0.f ? o[k] : 0.3f * o[k];
        float* orow = out + ((size_t)b * N_NODES + i) * FEAT + c8;
        *(float4*)orow = make_float4(o[0], o[1], o[2], o[3]);
        *(float4*)(orow + 4) = make_float4(o[4], o[5], o[6], o[7]);
    }
}

// ---------------------------------------------------------------------------
extern "C" void kernel_launch(void* const* d_in, const int* in_sizes, int n_in,
                              void* d_out, int out_size, void* d_ws, size_t ws_size,
                              hipStream_t stream) {
    const float* x     = (const float*)d_in[0];
    const float* A     = (const float*)d_in[1];
    const float* W     = (const float*)d_in[2];
    const float* bias  = (const float*)d_in[3];
    const float* a_src = (const float*)d_in[4];
    const float* a_dst = (const float*)d_in[5];
    float* out = (float*)d_out;

    // workspace layout (~10.7 MB total)
    char* ws = (char*)d_ws;
    unsigned short* h = (unsigned short*)ws;                  // B*N*C bf16 (8.4 MB)
    float* es = (float*)(h + (size_t)BATCH * N_NODES * FEAT); // B*N floats
    float* ed = es + BATCH * N_NODES;                         // B*N floats
    int*   dg = (int*)(ed + BATCH * N_NODES);                 // N ints
    unsigned short* nb = (unsigned short*)(dg + N_NODES);     // N*CAP ushorts (2 MB)

    hipLaunchKernelGGL(prep, dim3(1536), dim3(256), 0, stream,
                       x, A, W, a_src, a_dst, h, es, ed, nb, dg);
    hipLaunchKernelGGL(aggregate, dim3(BATCH * N_NODES / 4), dim3(256), 0, stream,
                       h, es, ed, nb, dg, bias, out);
}

// Round 7
// 65.645 us; speedup vs baseline: 1.2854x; 1.0016x over previous
//
#include <hip/hip_runtime.h>
#include <hip/hip_bf16.h>

#define N_NODES 4096
#define BATCH 8
#define FEAT 128
#define CAPQ 128     // per-quarter-row cap
#define CAP 256      // per-row cap

typedef float v2f __attribute__((ext_vector_type(2)));

__device__ __forceinline__ unsigned short f2bf(float f) {
    unsigned int u = __float_as_uint(f);
    u += 0x7fffu + ((u >> 16) & 1u);   // RNE (finite, non-NaN here)
    return (unsigned short)(u >> 16);
}

// acc[0..3] (float2 pairs) += p * bf16x8(hv)
__device__ __forceinline__ void fma8v(v2f* acc, v2f pp, uint4 hv) {
    unsigned int u;
    v2f t;
    u = hv.x; t[0] = __uint_as_float(u << 16); t[1] = __uint_as_float(u & 0xffff0000u);
    acc[0] += pp * t;
    u = hv.y; t[0] = __uint_as_float(u << 16); t[1] = __uint_as_float(u & 0xffff0000u);
    acc[1] += pp * t;
    u = hv.z; t[0] = __uint_as_float(u << 16); t[1] = __uint_as_float(u & 0xffff0000u);
    acc[2] += pp * t;
    u = hv.w; t[0] = __uint_as_float(u << 16); t[1] = __uint_as_float(u & 0xffff0000u);
    acc[3] += pp * t;
}

// ---------------------------------------------------------------------------
// Kernel 1: A-scan, ONE BLOCK PER ROW. Wave w ballot-compacts the quarter
// A[i, w*1024 .. +1024) (4 unrolled float4 iterations -> 4 loads in flight
// before the ballot chain) into an LDS segment; segments merge via prefix
// and store coalesced to the global neighbor list. Serial chain per wave is
// 4 rounds (vs 16 in the wave-per-row variant that latency-serialized R6).
// ---------------------------------------------------------------------------
__global__ __launch_bounds__(256) void build_adj(const float* __restrict__ A,
                                                 unsigned short* __restrict__ nbr,
                                                 int* __restrict__ deg) {
    __shared__ unsigned short seg[4 * CAPQ];
    __shared__ int scnt[4];

    int tid = threadIdx.x;
    int lane = tid & 63;
    int w = tid >> 6;
    int i = blockIdx.x;

    {
        const float4* ar = (const float4*)(A + (size_t)i * N_NODES);
        unsigned long long below = (1ull << lane) - 1ull;
        int cnt = 0;
#pragma unroll
        for (int c0 = 0; c0 < 4; ++c0) {
            int idx = w * 256 + c0 * 64 + lane;
            float4 v = ar[idx];
            bool f0 = v.x > 0.f, f1 = v.y > 0.f, f2 = v.z > 0.f, f3 = v.w > 0.f;
            unsigned long long m0 = __ballot(f0), m1 = __ballot(f1),
                               m2 = __ballot(f2), m3 = __ballot(f3);
            int pos = cnt + (int)__popcll(m0 & below) + (int)__popcll(m1 & below)
                          + (int)__popcll(m2 & below) + (int)__popcll(m3 & below);
            int colb = 4 * idx;
            if (f0) { if (pos < CAPQ) seg[w * CAPQ + pos] = (unsigned short)(colb);     ++pos; }
            if (f1) { if (pos < CAPQ) seg[w * CAPQ + pos] = (unsigned short)(colb + 1); ++pos; }
            if (f2) { if (pos < CAPQ) seg[w * CAPQ + pos] = (unsigned short)(colb + 2); ++pos; }
            if (f3) { if (pos < CAPQ) seg[w * CAPQ + pos] = (unsigned short)(colb + 3); ++pos; }
            cnt += (int)__popcll(m0) + (int)__popcll(m1)
                 + (int)__popcll(m2) + (int)__popcll(m3);
        }
        if (lane == 0) scnt[w] = cnt < CAPQ ? cnt : CAPQ;
    }
    __syncthreads();

    int c0n = scnt[0], c1n = scnt[1], c2n = scnt[2], c3n = scnt[3];
    int off = (w > 0 ? c0n : 0) + (w > 1 ? c1n : 0) + (w > 2 ? c2n : 0);
    int cw = scnt[w];
    unsigned short* lst = nbr + (size_t)i * CAP;
    for (int t = lane; t < cw; t += 64) {
        int dst = off + t;
        if (dst < CAP) lst[dst] = seg[w * CAPQ + t];
    }
    if (tid == 0) {
        int d = c0n + c1n + c2n + c3n;
        deg[i] = d < CAP ? d : CAP;
    }
}

// ---------------------------------------------------------------------------
// Kernel 2: h = x @ W (bf16 out) + fp32 e_src/e_dst epilogue.
// W in LDS, SPLIT float4 layout Wl4[k*32 + part*16 + colg]: the 16 colg
// lanes read at 16B stride -> start banks 4l mod 32 -> free 2-way aliasing
// only (R3's 32B-stride layout was a 4-way conflict). 4 rows x 8 cols per
// thread, 64 rows/block, 512 blocks.
// ---------------------------------------------------------------------------
__global__ __launch_bounds__(256) void gemm_h(const float* __restrict__ x,
                                              const float* __restrict__ W,
                                              const float* __restrict__ a_src,
                                              const float* __restrict__ a_dst,
                                              unsigned short* __restrict__ h,
                                              float* __restrict__ es,
                                              float* __restrict__ ed) {
    __shared__ float4 Wl4[FEAT * 32];   // 64 KB
    int tid = threadIdx.x;
    {
        const float4* Wv = (const float4*)W;   // (k, j): j = 0..31, cols 4j..4j+3
        for (int i = tid; i < FEAT * 32; i += 256) {
            int k = i >> 5, j = i & 31;
            Wl4[k * 32 + ((j & 1) << 4) + (j >> 1)] = Wv[i];
        }
    }
    __syncthreads();

    int colg = tid & 15;
    int rowg = tid >> 4;
    int c0 = colg * 8;
    int m0 = blockIdx.x * 64 + rowg * 4;
    const float* xr = x + (size_t)m0 * FEAT;

    float acc[4][8];
#pragma unroll
    for (int i = 0; i < 4; ++i)
#pragma unroll
        for (int c = 0; c < 8; ++c) acc[i][c] = 0.f;

    for (int k = 0; k < FEAT; k += 4) {
        float4 xv[4];
#pragma unroll
        for (int i = 0; i < 4; ++i) xv[i] = *(const float4*)(xr + i * FEAT + k);
#pragma unroll
        for (int kk = 0; kk < 4; ++kk) {
            float4 wa = Wl4[(k + kk) * 32 + colg];
            float4 wb = Wl4[(k + kk) * 32 + 16 + colg];
#pragma unroll
            for (int i = 0; i < 4; ++i) {
                float xs = (&xv[i].x)[kk];
                acc[i][0] += xs * wa.x; acc[i][1] += xs * wa.y;
                acc[i][2] += xs * wa.z; acc[i][3] += xs * wa.w;
                acc[i][4] += xs * wb.x; acc[i][5] += xs * wb.y;
                acc[i][6] += xs * wb.z; acc[i][7] += xs * wb.w;
            }
        }
    }

    float as[8], ad[8];
#pragma unroll
    for (int c = 0; c < 8; ++c) { as[c] = a_src[c0 + c]; ad[c] = a_dst[c0 + c]; }

#pragma unroll
    for (int i = 0; i < 4; ++i) {
        uint4 pk;
        pk.x = (unsigned int)f2bf(acc[i][0]) | ((unsigned int)f2bf(acc[i][1]) << 16);
        pk.y = (unsigned int)f2bf(acc[i][2]) | ((unsigned int)f2bf(acc[i][3]) << 16);
        pk.z = (unsigned int)f2bf(acc[i][4]) | ((unsigned int)f2bf(acc[i][5]) << 16);
        pk.w = (unsigned int)f2bf(acc[i][6]) | ((unsigned int)f2bf(acc[i][7]) << 16);
        *(uint4*)(h + (size_t)(m0 + i) * FEAT + c0) = pk;

        float ps = 0.f, pd = 0.f;
#pragma unroll
        for (int c = 0; c < 8; ++c) { ps += acc[i][c] * as[c]; pd += acc[i][c] * ad[c]; }
#pragma unroll
        for (int off = 8; off >= 1; off >>= 1) {
            ps += __shfl_xor(ps, off);
            pd += __shfl_xor(pd, off);
        }
        if (colg == 0) { es[m0 + i] = ps; ed[m0 + i] = pd; }
    }
}

// ---------------------------------------------------------------------------
// Kernel 3: per (b,i) masked-softmax + neighbor aggregation.
// One wave per output row; z/col cached in regs from the max pass.
// Pass 2: 4 groups of 16 lanes x 2 chains = 8 neighbors/iter, 8 bf16 cols
// per lane as one uint4, float2 packed FMA.
// blockIdx&7 = batch -> XCD affinity (h[b] = 1MB, fits per-XCD 4MB L2).
// ---------------------------------------------------------------------------
__global__ __launch_bounds__(256) void aggregate(const unsigned short* __restrict__ h,
                                                 const float* __restrict__ es,
                                                 const float* __restrict__ ed,
                                                 const unsigned short* __restrict__ nbr,
                                                 const int* __restrict__ deg,
                                                 const float* __restrict__ bias,
                                                 float* __restrict__ out) {
    int lane = threadIdx.x & 63;
    int g = lane >> 4;             // neighbor slot within iteration
    int c8 = (lane & 15) * 8;      // this lane's 8 output columns
    int b = blockIdx.x & 7;
    int i = (blockIdx.x >> 3) * 4 + (threadIdx.x >> 6);

    int d = deg[i];
    const unsigned short* lst = nbr + (size_t)i * CAP;
    float esv = es[b * N_NODES + i];
    const float* edb = ed + b * N_NODES;

    float zv0 = -1e30f, zv1 = -1e30f, zv2 = -1e30f, zv3 = -1e30f;
    int cv0 = 0, cv1 = 0, cv2 = 0, cv3 = 0;
    float m = -1e30f;
#define PASS1(c, zz, cc)                                            \
    if (c * 64 < d) {                                               \
        int j = c * 64 + lane;                                      \
        if (j < d) {                                                \
            cc = lst[j];                                            \
            float z0 = esv + edb[cc];                               \
            zz = z0 > 0.f ? z0 : 0.2f * z0;                         \
        }                                                           \
        m = fmaxf(m, zz);                                           \
    }
    PASS1(0, zv0, cv0)
    PASS1(1, zv1, cv1)
    PASS1(2, zv2, cv2)
    PASS1(3, zv3, cv3)
#undef PASS1
#pragma unroll
    for (int off = 32; off >= 1; off >>= 1) m = fmaxf(m, __shfl_xor(m, off));

    const unsigned short* hb = h + (size_t)b * N_NODES * FEAT;
    v2f acc0[4], acc1[4];
#pragma unroll
    for (int k = 0; k < 4; ++k) { acc0[k] = (v2f)(0.f); acc1[k] = (v2f)(0.f); }
    float s = 0.f;
#define PASS2(c, zz, cc)                                                        \
    if (c * 64 < d) {                                                           \
        float p = __expf(zz - m);  /* inactive lanes: exp(-1e30-m)==0 */        \
        s += p;                                                                 \
        int n = d - c * 64; if (n > 64) n = 64;                                 \
        int nn = (n + 7) & ~7;                                                  \
        for (int jj = 0; jj < nn; jj += 8) {                                    \
            int j0 = jj + g, j1 = jj + 4 + g;                                   \
            float p0 = __shfl(p, j0); int cj0 = __shfl(cc, j0);                 \
            float p1 = __shfl(p, j1); int cj1 = __shfl(cc, j1);                 \
            uint4 h0 = *(const uint4*)(hb + (size_t)cj0 * FEAT + c8);           \
            uint4 h1 = *(const uint4*)(hb + (size_t)cj1 * FEAT + c8);           \
            v2f pp0; pp0[0] = p0; pp0[1] = p0;                                  \
            v2f pp1; pp1[0] = p1; pp1[1] = p1;                                  \
            fma8v(acc0, pp0, h0);                                               \
            fma8v(acc1, pp1, h1);                                               \
        }                                                                       \
    }
    PASS2(0, zv0, cv0)
    PASS2(1, zv1, cv1)
    PASS2(2, zv2, cv2)
    PASS2(3, zv3, cv3)
#undef PASS2

#pragma unroll
    for (int off = 32; off >= 1; off >>= 1) s += __shfl_xor(s, off);
    float inv = 1.0f / s;

#pragma unroll
    for (int k = 0; k < 4; ++k) acc0[k] += acc1[k];
#pragma unroll
    for (int k = 0; k < 4; ++k) {
        acc0[k][0] += __shfl_xor(acc0[k][0], 16);
        acc0[k][1] += __shfl_xor(acc0[k][1], 16);
        acc0[k][0] += __shfl_xor(acc0[k][0], 32);
        acc0[k][1] += __shfl_xor(acc0[k][1], 32);
    }

    if (lane < 16) {
        float4 b0 = *(const float4*)(bias + c8);
        float4 b1 = *(const float4*)(bias + c8 + 4);
        float o[8];
        o[0] = acc0[0][0] * inv + b0.x; o[1] = acc0[0][1] * inv + b0.y;
        o[2] = acc0[1][0] * inv + b0.z; o[3] = acc0[1][1] * inv + b0.w;
        o[4] = acc0[2][0] * inv + b1.x; o[5] = acc0[2][1] * inv + b1.y;
        o[6] = acc0[3][0] * inv + b1.z; o[7] = acc0[3][1] * inv + b1.w;
#pragma unroll
        for (int k = 0; k < 8; ++k) o[k] = o[k] > 0.f ? o[k] : 0.3f * o[k];
        float* orow = out + ((size_t)b * N_NODES + i) * FEAT + c8;
        *(float4*)orow = make_float4(o[0], o[1], o[2], o[3]);
        *(float4*)(orow + 4) = make_float4(o[4], o[5], o[6], o[7]);
    }
}

// ---------------------------------------------------------------------------
extern "C" void kernel_launch(void* const* d_in, const int* in_sizes, int n_in,
                              void* d_out, int out_size, void* d_ws, size_t ws_size,
                              hipStream_t stream) {
    const float* x     = (const float*)d_in[0];
    const float* A     = (const float*)d_in[1];
    const float* W     = (const float*)d_in[2];
    const float* bias  = (const float*)d_in[3];
    const float* a_src = (const float*)d_in[4];
    const float* a_dst = (const float*)d_in[5];
    float* out = (float*)d_out;

    // workspace layout (~10.7 MB total)
    char* ws = (char*)d_ws;
    unsigned short* h = (unsigned short*)ws;                  // B*N*C bf16 (8.4 MB)
    float* es = (float*)(h + (size_t)BATCH * N_NODES * FEAT); // B*N floats
    float* ed = es + BATCH * N_NODES;                         // B*N floats
    int*   dg = (int*)(ed + BATCH * N_NODES);                 // N ints
    unsigned short* nb = (unsigned short*)(dg + N_NODES);     // N*CAP ushorts (2 MB)

    hipLaunchKernelGGL(build_adj, dim3(N_NODES), dim3(256), 0, stream, A, nb, dg);
    hipLaunchKernelGGL(gemm_h, dim3(BATCH * N_NODES / 64), dim3(256), 0, stream,
                       x, W, a_src, a_dst, h, es, ed);
    hipLaunchKernelGGL(aggregate, dim3(BATCH * N_NODES / 4), dim3(256), 0, stream,
                       h, es, ed, nb, dg, bias, out);
}

// Round 8
// 64.989 us; speedup vs baseline: 1.2984x; 1.0101x over previous
//
#include <hip/hip_runtime.h>
#include <hip/hip_bf16.h>

#define N_NODES 4096
#define BATCH 8
#define FEAT 128
#define CAP 256      // per-row cap

typedef float v2f __attribute__((ext_vector_type(2)));

__device__ __forceinline__ unsigned short f2bf(float f) {
    unsigned int u = __float_as_uint(f);
    u += 0x7fffu + ((u >> 16) & 1u);   // RNE (finite, non-NaN here)
    return (unsigned short)(u >> 16);
}

// acc[0..3] (float2 pairs) += p * bf16x8(hv)
__device__ __forceinline__ void fma8v(v2f* acc, v2f pp, uint4 hv) {
    unsigned int u;
    v2f t;
    u = hv.x; t[0] = __uint_as_float(u << 16); t[1] = __uint_as_float(u & 0xffff0000u);
    acc[0] += pp * t;
    u = hv.y; t[0] = __uint_as_float(u << 16); t[1] = __uint_as_float(u & 0xffff0000u);
    acc[1] += pp * t;
    u = hv.z; t[0] = __uint_as_float(u << 16); t[1] = __uint_as_float(u & 0xffff0000u);
    acc[2] += pp * t;
    u = hv.w; t[0] = __uint_as_float(u << 16); t[1] = __uint_as_float(u & 0xffff0000u);
    acc[3] += pp * t;
}

// ---------------------------------------------------------------------------
// Kernel 1: A-scan. One wave per row. PRELOAD the wave's entire row slice
// (16 x float4 = 64 VGPRs) in a dependency-free burst, THEN ballot-compact
// from registers. 16KB in flight per wave x 16 waves/CU >> BW*latency
// product -> streams at HBM rate (previous interleaved versions kept only
// ~1-2 loads outstanding -> ~2.5 TB/s ceiling, ~28us).
// ---------------------------------------------------------------------------
__global__ __launch_bounds__(256) void build_adj(const float* __restrict__ A,
                                                 unsigned short* __restrict__ nbr,
                                                 int* __restrict__ deg) {
    int lane = threadIdx.x & 63;
    int row = blockIdx.x * 4 + (threadIdx.x >> 6);
    const float4* ar = (const float4*)(A + (size_t)row * N_NODES);

    // burst: 16 independent loads, no consumer in between
    float4 v[16];
#pragma unroll
    for (int c = 0; c < 16; ++c) v[c] = ar[c * 64 + lane];

    unsigned short* lst = nbr + (size_t)row * CAP;
    unsigned long long below = (1ull << lane) - 1ull;
    int cnt = 0;
#pragma unroll
    for (int c = 0; c < 16; ++c) {
        bool f0 = v[c].x > 0.f, f1 = v[c].y > 0.f, f2 = v[c].z > 0.f, f3 = v[c].w > 0.f;
        unsigned long long m0 = __ballot(f0), m1 = __ballot(f1),
                           m2 = __ballot(f2), m3 = __ballot(f3);
        int pos = cnt + (int)__popcll(m0 & below) + (int)__popcll(m1 & below)
                      + (int)__popcll(m2 & below) + (int)__popcll(m3 & below);
        int colb = 4 * (c * 64 + lane);
        if (f0) { if (pos < CAP) lst[pos] = (unsigned short)(colb);     ++pos; }
        if (f1) { if (pos < CAP) lst[pos] = (unsigned short)(colb + 1); ++pos; }
        if (f2) { if (pos < CAP) lst[pos] = (unsigned short)(colb + 2); ++pos; }
        if (f3) { if (pos < CAP) lst[pos] = (unsigned short)(colb + 3); ++pos; }
        cnt += (int)__popcll(m0) + (int)__popcll(m1)
             + (int)__popcll(m2) + (int)__popcll(m3);
    }
    if (lane == 0) deg[row] = cnt < CAP ? cnt : CAP;
}

// ---------------------------------------------------------------------------
// Kernel 2: h = x @ W (bf16 out) + fp32 e_src/e_dst epilogue.
// W in LDS, split-float4 bank-free layout (R5-verified 0 conflicts).
// 512-THREAD blocks (vs 256 in R5): 128 rows/block, 256 blocks ->
// 2 blocks/CU x 8 waves = 16 waves/CU (R5 had 8 -> latency-starved at
// ~20us). W staging also amortized 2x.
// ---------------------------------------------------------------------------
__global__ __launch_bounds__(512) void gemm_h(const float* __restrict__ x,
                                              const float* __restrict__ W,
                                              const float* __restrict__ a_src,
                                              const float* __restrict__ a_dst,
                                              unsigned short* __restrict__ h,
                                              float* __restrict__ es,
                                              float* __restrict__ ed) {
    __shared__ float4 Wl4[FEAT * 32];   // 64 KB
    int tid = threadIdx.x;
    {
        const float4* Wv = (const float4*)W;   // (k, j): j = 0..31, cols 4j..4j+3
        for (int i = tid; i < FEAT * 32; i += 512) {
            int k = i >> 5, j = i & 31;
            Wl4[k * 32 + ((j & 1) << 4) + (j >> 1)] = Wv[i];
        }
    }
    __syncthreads();

    int colg = tid & 15;
    int rowg = tid >> 4;               // 0..31
    int c0 = colg * 8;
    int m0 = blockIdx.x * 128 + rowg * 4;
    const float* xr = x + (size_t)m0 * FEAT;

    float acc[4][8];
#pragma unroll
    for (int i = 0; i < 4; ++i)
#pragma unroll
        for (int c = 0; c < 8; ++c) acc[i][c] = 0.f;

    for (int k = 0; k < FEAT; k += 4) {
        float4 xv[4];
#pragma unroll
        for (int i = 0; i < 4; ++i) xv[i] = *(const float4*)(xr + i * FEAT + k);
#pragma unroll
        for (int kk = 0; kk < 4; ++kk) {
            float4 wa = Wl4[(k + kk) * 32 + colg];
            float4 wb = Wl4[(k + kk) * 32 + 16 + colg];
#pragma unroll
            for (int i = 0; i < 4; ++i) {
                float xs = (&xv[i].x)[kk];
                acc[i][0] += xs * wa.x; acc[i][1] += xs * wa.y;
                acc[i][2] += xs * wa.z; acc[i][3] += xs * wa.w;
                acc[i][4] += xs * wb.x; acc[i][5] += xs * wb.y;
                acc[i][6] += xs * wb.z; acc[i][7] += xs * wb.w;
            }
        }
    }

    float as[8], ad[8];
#pragma unroll
    for (int c = 0; c < 8; ++c) { as[c] = a_src[c0 + c]; ad[c] = a_dst[c0 + c]; }

#pragma unroll
    for (int i = 0; i < 4; ++i) {
        uint4 pk;
        pk.x = (unsigned int)f2bf(acc[i][0]) | ((unsigned int)f2bf(acc[i][1]) << 16);
        pk.y = (unsigned int)f2bf(acc[i][2]) | ((unsigned int)f2bf(acc[i][3]) << 16);
        pk.z = (unsigned int)f2bf(acc[i][4]) | ((unsigned int)f2bf(acc[i][5]) << 16);
        pk.w = (unsigned int)f2bf(acc[i][6]) | ((unsigned int)f2bf(acc[i][7]) << 16);
        *(uint4*)(h + (size_t)(m0 + i) * FEAT + c0) = pk;

        float ps = 0.f, pd = 0.f;
#pragma unroll
        for (int c = 0; c < 8; ++c) { ps += acc[i][c] * as[c]; pd += acc[i][c] * ad[c]; }
#pragma unroll
        for (int off = 8; off >= 1; off >>= 1) {
            ps += __shfl_xor(ps, off);
            pd += __shfl_xor(pd, off);
        }
        if (colg == 0) { es[m0 + i] = ps; ed[m0 + i] = pd; }
    }
}

// ---------------------------------------------------------------------------
// Kernel 3: per (b,i) masked-softmax + neighbor aggregation.
// One wave per output row; z/col cached in regs from the max pass.
// Pass 2: 4 groups of 16 lanes x 2 chains = 8 neighbors/iter, 8 bf16 cols
// per lane as one uint4, float2 packed FMA.
// blockIdx&7 = batch -> XCD affinity (h[b] = 1MB, fits per-XCD 4MB L2).
// ---------------------------------------------------------------------------
__global__ __launch_bounds__(256) void aggregate(const unsigned short* __restrict__ h,
                                                 const float* __restrict__ es,
                                                 const float* __restrict__ ed,
                                                 const unsigned short* __restrict__ nbr,
                                                 const int* __restrict__ deg,
                                                 const float* __restrict__ bias,
                                                 float* __restrict__ out) {
    int lane = threadIdx.x & 63;
    int g = lane >> 4;             // neighbor slot within iteration
    int c8 = (lane & 15) * 8;      // this lane's 8 output columns
    int b = blockIdx.x & 7;
    int i = (blockIdx.x >> 3) * 4 + (threadIdx.x >> 6);

    int d = deg[i];
    const unsigned short* lst = nbr + (size_t)i * CAP;
    float esv = es[b * N_NODES + i];
    const float* edb = ed + b * N_NODES;

    float zv0 = -1e30f, zv1 = -1e30f, zv2 = -1e30f, zv3 = -1e30f;
    int cv0 = 0, cv1 = 0, cv2 = 0, cv3 = 0;
    float m = -1e30f;
#define PASS1(c, zz, cc)                                            \
    if (c * 64 < d) {                                               \
        int j = c * 64 + lane;                                      \
        if (j < d) {                                                \
            cc = lst[j];                                            \
            float z0 = esv + edb[cc];                               \
            zz = z0 > 0.f ? z0 : 0.2f * z0;                         \
        }                                                           \
        m = fmaxf(m, zz);                                           \
    }
    PASS1(0, zv0, cv0)
    PASS1(1, zv1, cv1)
    PASS1(2, zv2, cv2)
    PASS1(3, zv3, cv3)
#undef PASS1
#pragma unroll
    for (int off = 32; off >= 1; off >>= 1) m = fmaxf(m, __shfl_xor(m, off));

    const unsigned short* hb = h + (size_t)b * N_NODES * FEAT;
    v2f acc0[4], acc1[4];
#pragma unroll
    for (int k = 0; k < 4; ++k) { acc0[k] = (v2f)(0.f); acc1[k] = (v2f)(0.f); }
    float s = 0.f;
#define PASS2(c, zz, cc)                                                        \
    if (c * 64 < d) {                                                           \
        float p = __expf(zz - m);  /* inactive lanes: exp(-1e30-m)==0 */        \
        s += p;                                                                 \
        int n = d - c * 64; if (n > 64) n = 64;                                 \
        int nn = (n + 7) & ~7;                                                  \
        for (int jj = 0; jj < nn; jj += 8) {                                    \
            int j0 = jj + g, j1 = jj + 4 + g;                                   \
            float p0 = __shfl(p, j0); int cj0 = __shfl(cc, j0);                 \
            float p1 = __shfl(p, j1); int cj1 = __shfl(cc, j1);                 \
            uint4 h0 = *(const uint4*)(hb + (size_t)cj0 * FEAT + c8);           \
            uint4 h1 = *(const uint4*)(hb + (size_t)cj1 * FEAT + c8);           \
            v2f pp0; pp0[0] = p0; pp0[1] = p0;                                  \
            v2f pp1; pp1[0] = p1; pp1[1] = p1;                                  \
            fma8v(acc0, pp0, h0);                                               \
            fma8v(acc1, pp1, h1);                                               \
        }                                                                       \
    }
    PASS2(0, zv0, cv0)
    PASS2(1, zv1, cv1)
    PASS2(2, zv2, cv2)
    PASS2(3, zv3, cv3)
#undef PASS2

#pragma unroll
    for (int off = 32; off >= 1; off >>= 1) s += __shfl_xor(s, off);
    float inv = 1.0f / s;

#pragma unroll
    for (int k = 0; k < 4; ++k) acc0[k] += acc1[k];
#pragma unroll
    for (int k = 0; k < 4; ++k) {
        acc0[k][0] += __shfl_xor(acc0[k][0], 16);
        acc0[k][1] += __shfl_xor(acc0[k][1], 16);
        acc0[k][0] += __shfl_xor(acc0[k][0], 32);
        acc0[k][1] += __shfl_xor(acc0[k][1], 32);
    }

    if (lane < 16) {
        float4 b0 = *(const float4*)(bias + c8);
        float4 b1 = *(const float4*)(bias + c8 + 4);
        float o[8];
        o[0] = acc0[0][0] * inv + b0.x; o[1] = acc0[0][1] * inv + b0.y;
        o[2] = acc0[1][0] * inv + b0.z; o[3] = acc0[1][1] * inv + b0.w;
        o[4] = acc0[2][0] * inv + b1.x; o[5] = acc0[2][1] * inv + b1.y;
        o[6] = acc0[3][0] * inv + b1.z; o[7] = acc0[3][1] * inv + b1.w;
#pragma unroll
        for (int k = 0; k < 8; ++k) o[k] = o[k] > 0.f ? o[k] : 0.3f * o[k];
        float* orow = out + ((size_t)b * N_NODES + i) * FEAT + c8;
        *(float4*)orow = make_float4(o[0], o[1], o[2], o[3]);
        *(float4*)(orow + 4) = make_float4(o[4], o[5], o[6], o[7]);
    }
}

// ---------------------------------------------------------------------------
extern "C" void kernel_launch(void* const* d_in, const int* in_sizes, int n_in,
                              void* d_out, int out_size, void* d_ws, size_t ws_size,
                              hipStream_t stream) {
    const float* x     = (const float*)d_in[0];
    const float* A     = (const float*)d_in[1];
    const float* W     = (const float*)d_in[2];
    const float* bias  = (const float*)d_in[3];
    const float* a_src = (const float*)d_in[4];
    const float* a_dst = (const float*)d_in[5];
    float* out = (float*)d_out;

    // workspace layout (~10.7 MB total)
    char* ws = (char*)d_ws;
    unsigned short* h = (unsigned short*)ws;                  // B*N*C bf16 (8.4 MB)
    float* es = (float*)(h + (size_t)BATCH * N_NODES * FEAT); // B*N floats
    float* ed = es + BATCH * N_NODES;                         // B*N floats
    int*   dg = (int*)(ed + BATCH * N_NODES);                 // N ints
    unsigned short* nb = (unsigned short*)(dg + N_NODES);     // N*CAP ushorts (2 MB)

    hipLaunchKernelGGL(build_adj, dim3(N_NODES / 4), dim3(256), 0, stream, A, nb, dg);
    hipLaunchKernelGGL(gemm_h, dim3(BATCH * N_NODES / 128), dim3(512), 0, stream,
                       x, W, a_src, a_dst, h, es, ed);
    hipLaunchKernelGGL(aggregate, dim3(BATCH * N_NODES / 4), dim3(256), 0, stream,
                       h, es, ed, nb, dg, bias, out);
}